// Round 6
// baseline (792.681 us; speedup 1.0000x reference)
//
#include <hip/hip_runtime.h>

#define N_NODES 50000
#define N_EDGES 1200000
#define F_IN 128
#define HID 64
#define N_CLASSES 10
#define N_GRAPHS 256
#define EPSF 1e-5f

// ---------------- CSR build ----------------

__global__ void k_hist(const int* __restrict__ dst, int* __restrict__ cnt) {
    int e = blockIdx.x * blockDim.x + threadIdx.x;
    if (e < N_EDGES) atomicAdd(&cnt[dst[e]], 1);
}

// single-block exclusive scan over N_NODES ints; also emits dinv = rsqrt(cnt+1)
__global__ __launch_bounds__(1024) void k_scan(const int* __restrict__ cnt,
                                               int* __restrict__ offs,
                                               int* __restrict__ cursor,
                                               float* __restrict__ dinv) {
    __shared__ int wsum[16];
    __shared__ int s_carry;
    int tid = threadIdx.x;
    int lane = tid & 63, wid = tid >> 6;
    if (tid == 0) s_carry = 0;
    __syncthreads();
    for (int base = 0; base < N_NODES; base += 1024) {
        int i = base + tid;
        int v = (i < N_NODES) ? cnt[i] : 0;
        if (i < N_NODES) dinv[i] = rsqrtf((float)v + 1.0f);
        int x = v;
        #pragma unroll
        for (int d = 1; d < 64; d <<= 1) {
            int y = __shfl_up(x, (unsigned)d);
            if (lane >= d) x += y;
        }
        if (lane == 63) wsum[wid] = x;
        __syncthreads();
        if (tid == 0) {
            int run = 0;
            for (int w = 0; w < 16; ++w) { int t = wsum[w]; wsum[w] = run; run += t; }
        }
        __syncthreads();
        int carry = s_carry;
        int excl = carry + wsum[wid] + (x - v);
        if (i < N_NODES) { offs[i] = excl; cursor[i] = excl; }
        __syncthreads();
        if (tid == 1023) s_carry = carry + wsum[15] + x;  // waves 0-14 excl + wave15 incl
        __syncthreads();
    }
    if (tid == 0) offs[N_NODES] = s_carry;
}

// csr[pos] = {src, bits(dinv[src])} — one 8B load in the gather loop gets index+weight
__global__ void k_fill(const int* __restrict__ esrc, const int* __restrict__ edst,
                       const float* __restrict__ dinv,
                       int* __restrict__ cursor, int2* __restrict__ csr) {
    int e = blockIdx.x * blockDim.x + threadIdx.x;
    if (e < N_EDGES) {
        int d = edst[e];
        int s = esrc[e];
        int pos = atomicAdd(&cursor[d], 1);
        csr[pos] = make_int2(s, __float_as_int(dinv[s]));
    }
}

// batch is sorted: gstart[g] = first node with batch >= g; gstart[N_GRAPHS] = N_NODES
__global__ void k_bounds(const int* __restrict__ batch, int* __restrict__ gstart) {
    int v = blockIdx.x * blockDim.x + threadIdx.x;
    if (v >= N_NODES) return;
    if (v == 0) {
        int b = batch[0];
        for (int g = 0; g <= b; ++g) gstart[g] = 0;
    } else {
        int b0 = batch[v - 1], b1 = batch[v];
        for (int g = b0 + 1; g <= b1; ++g) gstart[g] = v;
    }
    if (v == N_NODES - 1) {
        int b = batch[v];
        for (int g = b + 1; g <= N_GRAPHS; ++g) gstart[g] = N_NODES;
    }
}

// ---------------- dense layers ----------------

// out[N,64] = A'[N,K] @ W[K,64]; 64x64 block tile, 4x4 register micro-tile per thread.
// NORM: A' = relu(A*sc[k] + sh[k]) — prev layer's BN+ReLU fused into the A-stage.
template <int K, bool NORM>
__global__ __launch_bounds__(256) void k_gemm(const float* __restrict__ A,
                                              const float* __restrict__ W,
                                              float* __restrict__ out,
                                              const float* __restrict__ stats,
                                              const float* __restrict__ gamma,
                                              const float* __restrict__ beta) {
    __shared__ float sW[K * 64];
    __shared__ float sA[32][68];   // transposed A-chunk, padded (aligned b128, no conflicts)
    __shared__ float ssc[128];
    __shared__ float ssh[128];
    int tid = threadIdx.x;
    for (int i = tid; i < K * 64; i += 256) sW[i] = W[i];
    if (NORM && tid < K) {
        const float invN = 1.0f / (float)N_NODES;
        float mu = stats[tid] * invN;
        float var = stats[64 + tid] * invN - mu * mu;
        float sc = rsqrtf(var + EPSF) * gamma[tid];
        ssc[tid] = sc;
        ssh[tid] = beta[tid] - mu * sc;
    }
    __syncthreads();

    int row0 = blockIdx.x * 64;
    int c0 = (tid & 15) * 4;
    int r0 = (tid >> 4) * 4;
    float acc[4][4] = {};

    for (int k0 = 0; k0 < K; k0 += 32) {
        // stage 64 rows x 32 k, transposed; 2 float4 loads per thread
        #pragma unroll
        for (int i = 0; i < 2; ++i) {
            int idx = tid + i * 256;          // [0,512): row = idx/8, kq = idx%8
            int row = idx >> 3;
            int kq = idx & 7;
            int grow = row0 + row;
            float4 v = make_float4(0.f, 0.f, 0.f, 0.f);
            if (grow < N_NODES) v = *(const float4*)&A[(size_t)grow * K + k0 + kq * 4];
            if (NORM) {
                int kb = k0 + kq * 4;
                v.x = fmaxf(v.x * ssc[kb + 0] + ssh[kb + 0], 0.f);
                v.y = fmaxf(v.y * ssc[kb + 1] + ssh[kb + 1], 0.f);
                v.z = fmaxf(v.z * ssc[kb + 2] + ssh[kb + 2], 0.f);
                v.w = fmaxf(v.w * ssc[kb + 3] + ssh[kb + 3], 0.f);
            }
            sA[kq * 4 + 0][row] = v.x;
            sA[kq * 4 + 1][row] = v.y;
            sA[kq * 4 + 2][row] = v.z;
            sA[kq * 4 + 3][row] = v.w;
        }
        __syncthreads();
        #pragma unroll
        for (int k = 0; k < 32; ++k) {
            float4 a = *(const float4*)&sA[k][r0];
            float4 w = *(const float4*)&sW[(k0 + k) * 64 + c0];
            acc[0][0] += a.x * w.x; acc[0][1] += a.x * w.y; acc[0][2] += a.x * w.z; acc[0][3] += a.x * w.w;
            acc[1][0] += a.y * w.x; acc[1][1] += a.y * w.y; acc[1][2] += a.y * w.z; acc[1][3] += a.y * w.w;
            acc[2][0] += a.z * w.x; acc[2][1] += a.z * w.y; acc[2][2] += a.z * w.z; acc[2][3] += a.z * w.w;
            acc[3][0] += a.w * w.x; acc[3][1] += a.w * w.y; acc[3][2] += a.w * w.z; acc[3][3] += a.w * w.w;
        }
        __syncthreads();
    }
    #pragma unroll
    for (int i = 0; i < 4; ++i) {
        int row = row0 + r0 + i;
        if (row < N_NODES) {
            float4 v = make_float4(acc[i][0], acc[i][1], acc[i][2], acc[i][3]);
            *(float4*)&out[(size_t)row * 64 + c0] = v;
        }
    }
}

// hpre[v] = dv * (dv*hw[v] + sum_u w_u*hw[u]) + b ; accumulate BN stats (LDS-staged)
__global__ __launch_bounds__(256) void k_agg(const float* __restrict__ hw,
                                             const int* __restrict__ offs,
                                             const int2* __restrict__ csr,
                                             const float* __restrict__ dinv,
                                             const float* __restrict__ bias,
                                             float* __restrict__ hpre,
                                             float* __restrict__ stats) {
    __shared__ float sred[128];
    if (threadIdx.x < 128) sred[threadIdx.x] = 0.f;
    __syncthreads();
    int lane = threadIdx.x & 63;
    int wave = blockIdx.x * 4 + (threadIdx.x >> 6);
    int nw = gridDim.x * 4;
    float b = bias[lane];
    float lsum = 0.f, lsq = 0.f;
    for (int v = wave; v < N_NODES; v += nw) {
        float dv = dinv[v];
        int s = offs[v], e = offs[v + 1];
        float inner = dv * hw[(size_t)v * 64 + lane];
        int j = s;
        // 4 independent row-gathers in flight per iteration (MLP)
        for (; j + 4 <= e; j += 4) {
            int2 p0 = csr[j], p1 = csr[j + 1], p2 = csr[j + 2], p3 = csr[j + 3];
            float h0 = hw[(size_t)p0.x * 64 + lane];
            float h1 = hw[(size_t)p1.x * 64 + lane];
            float h2 = hw[(size_t)p2.x * 64 + lane];
            float h3 = hw[(size_t)p3.x * 64 + lane];
            inner += __int_as_float(p0.y) * h0;
            inner += __int_as_float(p1.y) * h1;
            inner += __int_as_float(p2.y) * h2;
            inner += __int_as_float(p3.y) * h3;
        }
        for (; j < e; ++j) {
            int2 p = csr[j];
            inner += __int_as_float(p.y) * hw[(size_t)p.x * 64 + lane];
        }
        float acc = dv * inner + b;
        hpre[(size_t)v * 64 + lane] = acc;
        lsum += acc;
        lsq += acc * acc;
    }
    atomicAdd(&sred[lane], lsum);
    atomicAdd(&sred[64 + lane], lsq);
    __syncthreads();
    if (threadIdx.x < 128) atomicAdd(&stats[threadIdx.x], sred[threadIdx.x]);
}

// one block per graph: norm+relu layer-3 rows, register max/sum over the graph's
// contiguous node range, LDS tree-reduce, then fused head MLP. Zero atomics.
__global__ __launch_bounds__(256) void k_pool(const float* __restrict__ hpre,
                                              const float* __restrict__ stats,
                                              const float* __restrict__ gamma,
                                              const float* __restrict__ beta,
                                              const int* __restrict__ gstart,
                                              const float* __restrict__ lw1,
                                              const float* __restrict__ lb1,
                                              const float* __restrict__ lw2,
                                              const float* __restrict__ lb2,
                                              float* __restrict__ out) {
    __shared__ float smax[4][64];
    __shared__ float ssum[4][64];
    __shared__ float emb[192];
    __shared__ float hid[64];
    int g = blockIdx.x;
    int lane = threadIdx.x & 63;
    int wid = threadIdx.x >> 6;
    int s = gstart[g], e = gstart[g + 1];

    const float invN = 1.0f / (float)N_NODES;
    float mu = stats[lane] * invN;
    float var = stats[64 + lane] * invN - mu * mu;
    float sc = rsqrtf(var + EPSF) * gamma[lane];
    float sh = beta[lane] - mu * sc;

    float mx = 0.f, sm = 0.f;  // post-relu values are >= 0; empty graph -> 0 (matches ref)
    for (int v = s + wid; v < e; v += 4) {
        float h = fmaxf(hpre[(size_t)v * 64 + lane] * sc + sh, 0.f);
        mx = fmaxf(mx, h);
        sm += h;
    }
    smax[wid][lane] = mx;
    ssum[wid][lane] = sm;
    __syncthreads();
    if (wid == 0) {
        float m = fmaxf(fmaxf(smax[0][lane], smax[1][lane]), fmaxf(smax[2][lane], smax[3][lane]));
        float su = ssum[0][lane] + ssum[1][lane] + ssum[2][lane] + ssum[3][lane];
        float inv = 1.0f / fmaxf((float)(e - s), 1.0f);
        emb[lane] = m;
        emb[64 + lane] = su * inv;
        emb[128 + lane] = su;
    }
    __syncthreads();
    if (wid == 0) {
        float acc = lb1[lane];
        #pragma unroll 4
        for (int k = 0; k < 192; ++k) acc += emb[k] * lw1[k * 64 + lane];
        hid[lane] = fmaxf(acc, 0.f);
    }
    __syncthreads();
    if (threadIdx.x < N_CLASSES) {
        int j = threadIdx.x;
        float o = lb2[j];
        #pragma unroll 8
        for (int k = 0; k < 64; ++k) o += hid[k] * lw2[k * 10 + j];
        out[(size_t)g * 10 + j] = o;
    }
}

// ---------------- launch ----------------

extern "C" void kernel_launch(void* const* d_in, const int* in_sizes, int n_in,
                              void* d_out, int out_size, void* d_ws, size_t ws_size,
                              hipStream_t stream) {
    const float* x     = (const float*)d_in[0];
    const int* eidx    = (const int*)d_in[1];
    const int* batch   = (const int*)d_in[2];
    const float* W1    = (const float*)d_in[3];
    const float* b1    = (const float*)d_in[4];
    const float* W2    = (const float*)d_in[5];
    const float* b2    = (const float*)d_in[6];
    const float* gamma = (const float*)d_in[7];
    const float* beta  = (const float*)d_in[8];
    const float* lw1   = (const float*)d_in[9];
    const float* lb1   = (const float*)d_in[10];
    const float* lw2   = (const float*)d_in[11];
    const float* lb2   = (const float*)d_in[12];
    float* out = (float*)d_out;

    const int* e_src = eidx;
    const int* e_dst = eidx + N_EDGES;

    char* p = (char*)d_ws;
    auto carve = [&](size_t bytes) { char* r = p; p += (bytes + 255) & ~(size_t)255; return r; };
    // zero-initialized region (one memset covers these)
    int*   cnt   = (int*)carve((size_t)N_NODES * 4);
    float* stats = (float*)carve(3 * 128 * 4);
    size_t zero_bytes = (size_t)(p - (char*)d_ws);
    // scratch (no init needed)
    int*   offs   = (int*)carve((size_t)(N_NODES + 1) * 4);
    int*   cursor = (int*)carve((size_t)N_NODES * 4);
    float* dinv   = (float*)carve((size_t)N_NODES * 4);
    int*   gstart = (int*)carve((size_t)(N_GRAPHS + 1) * 4);
    int2*  csr    = (int2*)carve((size_t)N_EDGES * 8);
    float* B0     = (float*)carve((size_t)N_NODES * 64 * 4);  // h @ W
    float* B1     = (float*)carve((size_t)N_NODES * 64 * 4);  // h_pre

    hipMemsetAsync(d_ws, 0, zero_bytes, stream);

    // CSR by destination (reused for all 3 layers) + graph segment bounds
    k_hist<<<(N_EDGES + 255) / 256, 256, 0, stream>>>(e_dst, cnt);
    k_scan<<<1, 1024, 0, stream>>>(cnt, offs, cursor, dinv);
    k_fill<<<(N_EDGES + 255) / 256, 256, 0, stream>>>(e_src, e_dst, dinv, cursor, csr);
    k_bounds<<<(N_NODES + 255) / 256, 256, 0, stream>>>(batch, gstart);

    const int GEMM_GRID = (N_NODES + 63) / 64;  // 782
    // layer 1
    k_gemm<128, false><<<GEMM_GRID, 256, 0, stream>>>(x, W1, B0, nullptr, nullptr, nullptr);
    k_agg<<<2048, 256, 0, stream>>>(B0, offs, csr, dinv, b1, B1, stats);
    // layer 2 (norm+relu of layer 1 fused into A-stage)
    k_gemm<64, true><<<GEMM_GRID, 256, 0, stream>>>(B1, W2, B0, stats, gamma, beta);
    k_agg<<<2048, 256, 0, stream>>>(B0, offs, csr, dinv, b2, B1, stats + 128);
    // layer 3 (norm+relu of layer 2 fused into A-stage)
    k_gemm<64, true><<<GEMM_GRID, 256, 0, stream>>>(B1, W2, B0, stats + 128, gamma, beta);
    k_agg<<<2048, 256, 0, stream>>>(B0, offs, csr, dinv, b2, B1, stats + 256);
    // norm+relu layer 3 + segmented pooling + head MLP (no atomics)
    k_pool<<<N_GRAPHS, 256, 0, stream>>>(B1, stats + 256, gamma, beta, gstart,
                                         lw1, lb1, lw2, lb2, out);
}

// Round 7
// 597.346 us; speedup vs baseline: 1.3270x; 1.3270x over previous
//
#include <hip/hip_runtime.h>

#define N_NODES 50000
#define N_EDGES 1200000
#define F_IN 128
#define HID 64
#define N_CLASSES 10
#define N_GRAPHS 256
#define EPSF 1e-5f

// ---------------- CSR build ----------------

__global__ void k_hist(const int* __restrict__ dst, int* __restrict__ cnt) {
    int e = blockIdx.x * blockDim.x + threadIdx.x;
    if (e < N_EDGES) atomicAdd(&cnt[dst[e]], 1);
}

// single-block exclusive scan over N_NODES ints; also emits dinv = rsqrt(cnt+1)
__global__ __launch_bounds__(1024) void k_scan(const int* __restrict__ cnt,
                                               int* __restrict__ offs,
                                               int* __restrict__ cursor,
                                               float* __restrict__ dinv) {
    __shared__ int wsum[16];
    __shared__ int s_carry;
    int tid = threadIdx.x;
    int lane = tid & 63, wid = tid >> 6;
    if (tid == 0) s_carry = 0;
    __syncthreads();
    for (int base = 0; base < N_NODES; base += 1024) {
        int i = base + tid;
        int v = (i < N_NODES) ? cnt[i] : 0;
        if (i < N_NODES) dinv[i] = rsqrtf((float)v + 1.0f);
        int x = v;
        #pragma unroll
        for (int d = 1; d < 64; d <<= 1) {
            int y = __shfl_up(x, (unsigned)d);
            if (lane >= d) x += y;
        }
        if (lane == 63) wsum[wid] = x;
        __syncthreads();
        if (tid == 0) {
            int run = 0;
            for (int w = 0; w < 16; ++w) { int t = wsum[w]; wsum[w] = run; run += t; }
        }
        __syncthreads();
        int carry = s_carry;
        int excl = carry + wsum[wid] + (x - v);
        if (i < N_NODES) { offs[i] = excl; cursor[i] = excl; }
        __syncthreads();
        if (tid == 1023) s_carry = carry + wsum[15] + x;  // waves 0-14 excl + wave15 incl
        __syncthreads();
    }
    if (tid == 0) offs[N_NODES] = s_carry;
}

// csr[pos] = {src, bits(dinv[src])} — one 8B load in the gather loop gets index+weight
__global__ void k_fill(const int* __restrict__ esrc, const int* __restrict__ edst,
                       const float* __restrict__ dinv,
                       int* __restrict__ cursor, int2* __restrict__ csr) {
    int e = blockIdx.x * blockDim.x + threadIdx.x;
    if (e < N_EDGES) {
        int d = edst[e];
        int s = esrc[e];
        int pos = atomicAdd(&cursor[d], 1);
        csr[pos] = make_int2(s, __float_as_int(dinv[s]));
    }
}

// batch is sorted: gstart[g] = first node with batch >= g; gstart[N_GRAPHS] = N_NODES
__global__ void k_bounds(const int* __restrict__ batch, int* __restrict__ gstart) {
    int v = blockIdx.x * blockDim.x + threadIdx.x;
    if (v >= N_NODES) return;
    if (v == 0) {
        int b = batch[0];
        for (int g = 0; g <= b; ++g) gstart[g] = 0;
    } else {
        int b0 = batch[v - 1], b1 = batch[v];
        for (int g = b0 + 1; g <= b1; ++g) gstart[g] = v;
    }
    if (v == N_NODES - 1) {
        int b = batch[v];
        for (int g = b + 1; g <= N_GRAPHS; ++g) gstart[g] = N_NODES;
    }
}

// ---------------- dense layers ----------------

// out[N,64] = A'[N,K] @ W[K,64]; 64x64 block tile, 4x4 register micro-tile per thread.
// NORM: A' = relu(A*sc[k] + sh[k]) — prev layer's BN+ReLU fused into the A-stage.
// __launch_bounds__(256,2) caps VGPR<=128; bounded unroll keeps <=8 b128 reads in
// flight (round-6 lesson: full unroll -> 256 VGPR + 165 MB scratch spill traffic).
template <int K, bool NORM>
__global__ __launch_bounds__(256, 2) void k_gemm(const float* __restrict__ A,
                                                 const float* __restrict__ W,
                                                 float* __restrict__ out,
                                                 const float* __restrict__ stats,
                                                 const float* __restrict__ gamma,
                                                 const float* __restrict__ beta) {
    __shared__ float sW[K * 64];
    __shared__ float sA[32][68];   // transposed A-chunk, +4 pad (aligned b128 reads)
    __shared__ float ssc[128];
    __shared__ float ssh[128];
    int tid = threadIdx.x;
    for (int i = tid; i < K * 16; i += 256) ((float4*)sW)[i] = ((const float4*)W)[i];
    if (NORM && tid < K) {
        const float invN = 1.0f / (float)N_NODES;
        float mu = stats[tid] * invN;
        float var = stats[64 + tid] * invN - mu * mu;
        float sc = rsqrtf(var + EPSF) * gamma[tid];
        ssc[tid] = sc;
        ssh[tid] = beta[tid] - mu * sc;
    }
    __syncthreads();

    int row0 = blockIdx.x * 64;
    int c0 = (tid & 15) * 4;
    int r0 = (tid >> 4) * 4;
    float acc[4][4] = {};

    #pragma unroll 1
    for (int k0 = 0; k0 < K; k0 += 32) {
        // stage 64 rows x 32 k, transposed; 2 float4 loads per thread
        #pragma unroll
        for (int i = 0; i < 2; ++i) {
            int idx = tid + i * 256;          // [0,512): row = idx/8, kq = idx%8
            int row = idx >> 3;
            int kq = idx & 7;
            int grow = row0 + row;
            float4 v = make_float4(0.f, 0.f, 0.f, 0.f);
            if (grow < N_NODES) v = *(const float4*)&A[(size_t)grow * K + k0 + kq * 4];
            if (NORM) {
                int kb = k0 + kq * 4;
                v.x = fmaxf(v.x * ssc[kb + 0] + ssh[kb + 0], 0.f);
                v.y = fmaxf(v.y * ssc[kb + 1] + ssh[kb + 1], 0.f);
                v.z = fmaxf(v.z * ssc[kb + 2] + ssh[kb + 2], 0.f);
                v.w = fmaxf(v.w * ssc[kb + 3] + ssh[kb + 3], 0.f);
            }
            sA[kq * 4 + 0][row] = v.x;
            sA[kq * 4 + 1][row] = v.y;
            sA[kq * 4 + 2][row] = v.z;
            sA[kq * 4 + 3][row] = v.w;
        }
        __syncthreads();
        #pragma unroll 4
        for (int k = 0; k < 32; ++k) {
            float4 a = *(const float4*)&sA[k][r0];
            float4 w = *(const float4*)&sW[(k0 + k) * 64 + c0];
            acc[0][0] += a.x * w.x; acc[0][1] += a.x * w.y; acc[0][2] += a.x * w.z; acc[0][3] += a.x * w.w;
            acc[1][0] += a.y * w.x; acc[1][1] += a.y * w.y; acc[1][2] += a.y * w.z; acc[1][3] += a.y * w.w;
            acc[2][0] += a.z * w.x; acc[2][1] += a.z * w.y; acc[2][2] += a.z * w.z; acc[2][3] += a.z * w.w;
            acc[3][0] += a.w * w.x; acc[3][1] += a.w * w.y; acc[3][2] += a.w * w.z; acc[3][3] += a.w * w.w;
        }
        __syncthreads();
    }
    #pragma unroll
    for (int i = 0; i < 4; ++i) {
        int row = row0 + r0 + i;
        if (row < N_NODES) {
            float4 v = make_float4(acc[i][0], acc[i][1], acc[i][2], acc[i][3]);
            *(float4*)&out[(size_t)row * 64 + c0] = v;
        }
    }
}

// hpre[v] = dv * (dv*hw[v] + sum_u w_u*hw[u]) + b ; accumulate BN stats (LDS-staged)
// 8-wide gather unroll: 8 independent row loads in flight per wave (latency hiding).
__global__ __launch_bounds__(256) void k_agg(const float* __restrict__ hw,
                                             const int* __restrict__ offs,
                                             const int2* __restrict__ csr,
                                             const float* __restrict__ dinv,
                                             const float* __restrict__ bias,
                                             float* __restrict__ hpre,
                                             float* __restrict__ stats) {
    __shared__ float sred[128];
    if (threadIdx.x < 128) sred[threadIdx.x] = 0.f;
    __syncthreads();
    int lane = threadIdx.x & 63;
    int wave = blockIdx.x * 4 + (threadIdx.x >> 6);
    int nw = gridDim.x * 4;
    float b = bias[lane];
    float lsum = 0.f, lsq = 0.f;
    for (int v = wave; v < N_NODES; v += nw) {
        float dv = dinv[v];
        int s = offs[v], e = offs[v + 1];
        float inner = dv * hw[(size_t)v * 64 + lane];
        int j = s;
        for (; j + 8 <= e; j += 8) {
            int2 p0 = csr[j],     p1 = csr[j + 1], p2 = csr[j + 2], p3 = csr[j + 3];
            int2 p4 = csr[j + 4], p5 = csr[j + 5], p6 = csr[j + 6], p7 = csr[j + 7];
            float h0 = hw[(size_t)p0.x * 64 + lane];
            float h1 = hw[(size_t)p1.x * 64 + lane];
            float h2 = hw[(size_t)p2.x * 64 + lane];
            float h3 = hw[(size_t)p3.x * 64 + lane];
            float h4 = hw[(size_t)p4.x * 64 + lane];
            float h5 = hw[(size_t)p5.x * 64 + lane];
            float h6 = hw[(size_t)p6.x * 64 + lane];
            float h7 = hw[(size_t)p7.x * 64 + lane];
            inner += __int_as_float(p0.y) * h0;
            inner += __int_as_float(p1.y) * h1;
            inner += __int_as_float(p2.y) * h2;
            inner += __int_as_float(p3.y) * h3;
            inner += __int_as_float(p4.y) * h4;
            inner += __int_as_float(p5.y) * h5;
            inner += __int_as_float(p6.y) * h6;
            inner += __int_as_float(p7.y) * h7;
        }
        for (; j + 4 <= e; j += 4) {
            int2 p0 = csr[j], p1 = csr[j + 1], p2 = csr[j + 2], p3 = csr[j + 3];
            float h0 = hw[(size_t)p0.x * 64 + lane];
            float h1 = hw[(size_t)p1.x * 64 + lane];
            float h2 = hw[(size_t)p2.x * 64 + lane];
            float h3 = hw[(size_t)p3.x * 64 + lane];
            inner += __int_as_float(p0.y) * h0;
            inner += __int_as_float(p1.y) * h1;
            inner += __int_as_float(p2.y) * h2;
            inner += __int_as_float(p3.y) * h3;
        }
        for (; j < e; ++j) {
            int2 p = csr[j];
            inner += __int_as_float(p.y) * hw[(size_t)p.x * 64 + lane];
        }
        float acc = dv * inner + b;
        hpre[(size_t)v * 64 + lane] = acc;
        lsum += acc;
        lsq += acc * acc;
    }
    atomicAdd(&sred[lane], lsum);
    atomicAdd(&sred[64 + lane], lsq);
    __syncthreads();
    if (threadIdx.x < 128) atomicAdd(&stats[threadIdx.x], sred[threadIdx.x]);
}

// one block per graph: norm+relu layer-3 rows, register max/sum over the graph's
// contiguous node range, LDS tree-reduce, then fused head MLP. Zero atomics.
__global__ __launch_bounds__(256) void k_pool(const float* __restrict__ hpre,
                                              const float* __restrict__ stats,
                                              const float* __restrict__ gamma,
                                              const float* __restrict__ beta,
                                              const int* __restrict__ gstart,
                                              const float* __restrict__ lw1,
                                              const float* __restrict__ lb1,
                                              const float* __restrict__ lw2,
                                              const float* __restrict__ lb2,
                                              float* __restrict__ out) {
    __shared__ float smax[4][64];
    __shared__ float ssum[4][64];
    __shared__ float emb[192];
    __shared__ float hid[64];
    int g = blockIdx.x;
    int lane = threadIdx.x & 63;
    int wid = threadIdx.x >> 6;
    int s = gstart[g], e = gstart[g + 1];

    const float invN = 1.0f / (float)N_NODES;
    float mu = stats[lane] * invN;
    float var = stats[64 + lane] * invN - mu * mu;
    float sc = rsqrtf(var + EPSF) * gamma[lane];
    float sh = beta[lane] - mu * sc;

    float mx = 0.f, sm = 0.f;  // post-relu values are >= 0; empty graph -> 0 (matches ref)
    for (int v = s + wid; v < e; v += 4) {
        float h = fmaxf(hpre[(size_t)v * 64 + lane] * sc + sh, 0.f);
        mx = fmaxf(mx, h);
        sm += h;
    }
    smax[wid][lane] = mx;
    ssum[wid][lane] = sm;
    __syncthreads();
    if (wid == 0) {
        float m = fmaxf(fmaxf(smax[0][lane], smax[1][lane]), fmaxf(smax[2][lane], smax[3][lane]));
        float su = ssum[0][lane] + ssum[1][lane] + ssum[2][lane] + ssum[3][lane];
        float inv = 1.0f / fmaxf((float)(e - s), 1.0f);
        emb[lane] = m;
        emb[64 + lane] = su * inv;
        emb[128 + lane] = su;
    }
    __syncthreads();
    if (wid == 0) {
        float acc = lb1[lane];
        #pragma unroll 4
        for (int k = 0; k < 192; ++k) acc += emb[k] * lw1[k * 64 + lane];
        hid[lane] = fmaxf(acc, 0.f);
    }
    __syncthreads();
    if (threadIdx.x < N_CLASSES) {
        int j = threadIdx.x;
        float o = lb2[j];
        #pragma unroll 8
        for (int k = 0; k < 64; ++k) o += hid[k] * lw2[k * 10 + j];
        out[(size_t)g * 10 + j] = o;
    }
}

// ---------------- launch ----------------

extern "C" void kernel_launch(void* const* d_in, const int* in_sizes, int n_in,
                              void* d_out, int out_size, void* d_ws, size_t ws_size,
                              hipStream_t stream) {
    const float* x     = (const float*)d_in[0];
    const int* eidx    = (const int*)d_in[1];
    const int* batch   = (const int*)d_in[2];
    const float* W1    = (const float*)d_in[3];
    const float* b1    = (const float*)d_in[4];
    const float* W2    = (const float*)d_in[5];
    const float* b2    = (const float*)d_in[6];
    const float* gamma = (const float*)d_in[7];
    const float* beta  = (const float*)d_in[8];
    const float* lw1   = (const float*)d_in[9];
    const float* lb1   = (const float*)d_in[10];
    const float* lw2   = (const float*)d_in[11];
    const float* lb2   = (const float*)d_in[12];
    float* out = (float*)d_out;

    const int* e_src = eidx;
    const int* e_dst = eidx + N_EDGES;

    char* p = (char*)d_ws;
    auto carve = [&](size_t bytes) { char* r = p; p += (bytes + 255) & ~(size_t)255; return r; };
    // zero-initialized region (one memset covers these)
    int*   cnt   = (int*)carve((size_t)N_NODES * 4);
    float* stats = (float*)carve(3 * 128 * 4);
    size_t zero_bytes = (size_t)(p - (char*)d_ws);
    // scratch (no init needed)
    int*   offs   = (int*)carve((size_t)(N_NODES + 1) * 4);
    int*   cursor = (int*)carve((size_t)N_NODES * 4);
    float* dinv   = (float*)carve((size_t)N_NODES * 4);
    int*   gstart = (int*)carve((size_t)(N_GRAPHS + 1) * 4);
    int2*  csr    = (int2*)carve((size_t)N_EDGES * 8);
    float* B0     = (float*)carve((size_t)N_NODES * 64 * 4);  // h @ W
    float* B1     = (float*)carve((size_t)N_NODES * 64 * 4);  // h_pre

    hipMemsetAsync(d_ws, 0, zero_bytes, stream);

    // CSR by destination (reused for all 3 layers) + graph segment bounds
    k_hist<<<(N_EDGES + 255) / 256, 256, 0, stream>>>(e_dst, cnt);
    k_scan<<<1, 1024, 0, stream>>>(cnt, offs, cursor, dinv);
    k_fill<<<(N_EDGES + 255) / 256, 256, 0, stream>>>(e_src, e_dst, dinv, cursor, csr);
    k_bounds<<<(N_NODES + 255) / 256, 256, 0, stream>>>(batch, gstart);

    const int GEMM_GRID = (N_NODES + 63) / 64;  // 782
    // layer 1
    k_gemm<128, false><<<GEMM_GRID, 256, 0, stream>>>(x, W1, B0, nullptr, nullptr, nullptr);
    k_agg<<<2048, 256, 0, stream>>>(B0, offs, csr, dinv, b1, B1, stats);
    // layer 2 (norm+relu of layer 1 fused into A-stage)
    k_gemm<64, true><<<GEMM_GRID, 256, 0, stream>>>(B1, W2, B0, stats, gamma, beta);
    k_agg<<<2048, 256, 0, stream>>>(B0, offs, csr, dinv, b2, B1, stats + 128);
    // layer 3 (norm+relu of layer 2 fused into A-stage)
    k_gemm<64, true><<<GEMM_GRID, 256, 0, stream>>>(B1, W2, B0, stats + 128, gamma, beta);
    k_agg<<<2048, 256, 0, stream>>>(B0, offs, csr, dinv, b2, B1, stats + 256);
    // norm+relu layer 3 + segmented pooling + head MLP (no atomics)
    k_pool<<<N_GRAPHS, 256, 0, stream>>>(B1, stats + 256, gamma, beta, gstart,
                                         lw1, lb1, lw2, lb2, out);
}

// Round 8
// 589.084 us; speedup vs baseline: 1.3456x; 1.0140x over previous
//
#include <hip/hip_runtime.h>
#include <hip/hip_bf16.h>

#define N_NODES 50000
#define N_EDGES 1200000
#define F_IN 128
#define HID 64
#define N_CLASSES 10
#define N_GRAPHS 256
#define EPSF 1e-5f

__device__ __forceinline__ float bf2f(unsigned short u) {
    return __uint_as_float((unsigned)u << 16);
}
__device__ __forceinline__ unsigned short f2bf(float f) {
    __hip_bfloat16 h = __float2bfloat16(f);  // RNE
    return *reinterpret_cast<unsigned short*>(&h);
}

// ---------------- CSR build ----------------

__global__ void k_hist(const int* __restrict__ dst, int* __restrict__ cnt) {
    int e = blockIdx.x * blockDim.x + threadIdx.x;
    if (e < N_EDGES) atomicAdd(&cnt[dst[e]], 1);
}

// single-block exclusive scan over N_NODES ints; also emits dinv = rsqrt(cnt+1)
__global__ __launch_bounds__(1024) void k_scan(const int* __restrict__ cnt,
                                               int* __restrict__ offs,
                                               int* __restrict__ cursor,
                                               float* __restrict__ dinv) {
    __shared__ int wsum[16];
    __shared__ int s_carry;
    int tid = threadIdx.x;
    int lane = tid & 63, wid = tid >> 6;
    if (tid == 0) s_carry = 0;
    __syncthreads();
    for (int base = 0; base < N_NODES; base += 1024) {
        int i = base + tid;
        int v = (i < N_NODES) ? cnt[i] : 0;
        if (i < N_NODES) dinv[i] = rsqrtf((float)v + 1.0f);
        int x = v;
        #pragma unroll
        for (int d = 1; d < 64; d <<= 1) {
            int y = __shfl_up(x, (unsigned)d);
            if (lane >= d) x += y;
        }
        if (lane == 63) wsum[wid] = x;
        __syncthreads();
        if (tid == 0) {
            int run = 0;
            for (int w = 0; w < 16; ++w) { int t = wsum[w]; wsum[w] = run; run += t; }
        }
        __syncthreads();
        int carry = s_carry;
        int excl = carry + wsum[wid] + (x - v);
        if (i < N_NODES) { offs[i] = excl; cursor[i] = excl; }
        __syncthreads();
        if (tid == 1023) s_carry = carry + wsum[15] + x;  // waves 0-14 excl + wave15 incl
        __syncthreads();
    }
    if (tid == 0) offs[N_NODES] = s_carry;
}

// csr[pos] = {src, bits(dinv[src])} — one 8B load in the gather loop gets index+weight
__global__ void k_fill(const int* __restrict__ esrc, const int* __restrict__ edst,
                       const float* __restrict__ dinv,
                       int* __restrict__ cursor, int2* __restrict__ csr) {
    int e = blockIdx.x * blockDim.x + threadIdx.x;
    if (e < N_EDGES) {
        int d = edst[e];
        int s = esrc[e];
        int pos = atomicAdd(&cursor[d], 1);
        csr[pos] = make_int2(s, __float_as_int(dinv[s]));
    }
}

// batch is sorted: gstart[g] = first node with batch >= g; gstart[N_GRAPHS] = N_NODES
__global__ void k_bounds(const int* __restrict__ batch, int* __restrict__ gstart) {
    int v = blockIdx.x * blockDim.x + threadIdx.x;
    if (v >= N_NODES) return;
    if (v == 0) {
        int b = batch[0];
        for (int g = 0; g <= b; ++g) gstart[g] = 0;
    } else {
        int b0 = batch[v - 1], b1 = batch[v];
        for (int g = b0 + 1; g <= b1; ++g) gstart[g] = v;
    }
    if (v == N_NODES - 1) {
        int b = batch[v];
        for (int g = b + 1; g <= N_GRAPHS; ++g) gstart[g] = N_NODES;
    }
}

// ---------------- dense layers ----------------

// out_bf[N,64] = bf16(A'[N,K] @ W[K,64]); 64x64 tile, 4x4 register micro-tile.
// NORM: A' = relu(A*sc[k] + sh[k]) — prev layer's BN+ReLU fused into the A-stage.
// bf16 output: the only consumer is k_agg's random gather — halves gather bytes
// and fits the 6.4 MB buffer in per-XCD L2. fp32 kept in acc/stats/hpre.
// __launch_bounds__(256,2) caps VGPR<=128; bounded unroll (round-6 spill lesson).
template <int K, bool NORM>
__global__ __launch_bounds__(256, 2) void k_gemm(const float* __restrict__ A,
                                                 const float* __restrict__ W,
                                                 unsigned short* __restrict__ out_bf,
                                                 const float* __restrict__ stats,
                                                 const float* __restrict__ gamma,
                                                 const float* __restrict__ beta) {
    __shared__ float sW[K * 64];
    __shared__ float sA[32][68];   // transposed A-chunk, +4 pad (aligned b128 reads)
    __shared__ float ssc[128];
    __shared__ float ssh[128];
    int tid = threadIdx.x;
    for (int i = tid; i < K * 16; i += 256) ((float4*)sW)[i] = ((const float4*)W)[i];
    if (NORM && tid < K) {
        const float invN = 1.0f / (float)N_NODES;
        float mu = stats[tid] * invN;
        float var = stats[64 + tid] * invN - mu * mu;
        float sc = rsqrtf(var + EPSF) * gamma[tid];
        ssc[tid] = sc;
        ssh[tid] = beta[tid] - mu * sc;
    }
    __syncthreads();

    int row0 = blockIdx.x * 64;
    int c0 = (tid & 15) * 4;
    int r0 = (tid >> 4) * 4;
    float acc[4][4] = {};

    #pragma unroll 1
    for (int k0 = 0; k0 < K; k0 += 32) {
        #pragma unroll
        for (int i = 0; i < 2; ++i) {
            int idx = tid + i * 256;          // [0,512): row = idx/8, kq = idx%8
            int row = idx >> 3;
            int kq = idx & 7;
            int grow = row0 + row;
            float4 v = make_float4(0.f, 0.f, 0.f, 0.f);
            if (grow < N_NODES) v = *(const float4*)&A[(size_t)grow * K + k0 + kq * 4];
            if (NORM) {
                int kb = k0 + kq * 4;
                v.x = fmaxf(v.x * ssc[kb + 0] + ssh[kb + 0], 0.f);
                v.y = fmaxf(v.y * ssc[kb + 1] + ssh[kb + 1], 0.f);
                v.z = fmaxf(v.z * ssc[kb + 2] + ssh[kb + 2], 0.f);
                v.w = fmaxf(v.w * ssc[kb + 3] + ssh[kb + 3], 0.f);
            }
            sA[kq * 4 + 0][row] = v.x;
            sA[kq * 4 + 1][row] = v.y;
            sA[kq * 4 + 2][row] = v.z;
            sA[kq * 4 + 3][row] = v.w;
        }
        __syncthreads();
        #pragma unroll 4
        for (int k = 0; k < 32; ++k) {
            float4 a = *(const float4*)&sA[k][r0];
            float4 w = *(const float4*)&sW[(k0 + k) * 64 + c0];
            acc[0][0] += a.x * w.x; acc[0][1] += a.x * w.y; acc[0][2] += a.x * w.z; acc[0][3] += a.x * w.w;
            acc[1][0] += a.y * w.x; acc[1][1] += a.y * w.y; acc[1][2] += a.y * w.z; acc[1][3] += a.y * w.w;
            acc[2][0] += a.z * w.x; acc[2][1] += a.z * w.y; acc[2][2] += a.z * w.z; acc[2][3] += a.z * w.w;
            acc[3][0] += a.w * w.x; acc[3][1] += a.w * w.y; acc[3][2] += a.w * w.z; acc[3][3] += a.w * w.w;
        }
        __syncthreads();
    }
    #pragma unroll
    for (int i = 0; i < 4; ++i) {
        int row = row0 + r0 + i;
        if (row < N_NODES) {
            ushort4 o;
            o.x = f2bf(acc[i][0]); o.y = f2bf(acc[i][1]);
            o.z = f2bf(acc[i][2]); o.w = f2bf(acc[i][3]);
            *(ushort4*)&out_bf[(size_t)row * 64 + c0] = o;  // 8B aligned (c0%4==0)
        }
    }
}

// hpre[v] = dv * (dv*hw[v] + sum_u w_u*hw[u]) + b ; hw is bf16, accum fp32.
// 8-wide gather unroll: 8 independent row loads in flight per wave.
__global__ __launch_bounds__(256) void k_agg(const unsigned short* __restrict__ hw,
                                             const int* __restrict__ offs,
                                             const int2* __restrict__ csr,
                                             const float* __restrict__ dinv,
                                             const float* __restrict__ bias,
                                             float* __restrict__ hpre,
                                             float* __restrict__ stats) {
    __shared__ float sred[128];
    if (threadIdx.x < 128) sred[threadIdx.x] = 0.f;
    __syncthreads();
    int lane = threadIdx.x & 63;
    int wave = blockIdx.x * 4 + (threadIdx.x >> 6);
    int nw = gridDim.x * 4;
    float b = bias[lane];
    float lsum = 0.f, lsq = 0.f;
    for (int v = wave; v < N_NODES; v += nw) {
        float dv = dinv[v];
        int s = offs[v], e = offs[v + 1];
        float inner = dv * bf2f(hw[(size_t)v * 64 + lane]);
        int j = s;
        for (; j + 8 <= e; j += 8) {
            int2 p0 = csr[j],     p1 = csr[j + 1], p2 = csr[j + 2], p3 = csr[j + 3];
            int2 p4 = csr[j + 4], p5 = csr[j + 5], p6 = csr[j + 6], p7 = csr[j + 7];
            unsigned short h0 = hw[(size_t)p0.x * 64 + lane];
            unsigned short h1 = hw[(size_t)p1.x * 64 + lane];
            unsigned short h2 = hw[(size_t)p2.x * 64 + lane];
            unsigned short h3 = hw[(size_t)p3.x * 64 + lane];
            unsigned short h4 = hw[(size_t)p4.x * 64 + lane];
            unsigned short h5 = hw[(size_t)p5.x * 64 + lane];
            unsigned short h6 = hw[(size_t)p6.x * 64 + lane];
            unsigned short h7 = hw[(size_t)p7.x * 64 + lane];
            inner += __int_as_float(p0.y) * bf2f(h0);
            inner += __int_as_float(p1.y) * bf2f(h1);
            inner += __int_as_float(p2.y) * bf2f(h2);
            inner += __int_as_float(p3.y) * bf2f(h3);
            inner += __int_as_float(p4.y) * bf2f(h4);
            inner += __int_as_float(p5.y) * bf2f(h5);
            inner += __int_as_float(p6.y) * bf2f(h6);
            inner += __int_as_float(p7.y) * bf2f(h7);
        }
        for (; j + 4 <= e; j += 4) {
            int2 p0 = csr[j], p1 = csr[j + 1], p2 = csr[j + 2], p3 = csr[j + 3];
            unsigned short h0 = hw[(size_t)p0.x * 64 + lane];
            unsigned short h1 = hw[(size_t)p1.x * 64 + lane];
            unsigned short h2 = hw[(size_t)p2.x * 64 + lane];
            unsigned short h3 = hw[(size_t)p3.x * 64 + lane];
            inner += __int_as_float(p0.y) * bf2f(h0);
            inner += __int_as_float(p1.y) * bf2f(h1);
            inner += __int_as_float(p2.y) * bf2f(h2);
            inner += __int_as_float(p3.y) * bf2f(h3);
        }
        for (; j < e; ++j) {
            int2 p = csr[j];
            inner += __int_as_float(p.y) * bf2f(hw[(size_t)p.x * 64 + lane]);
        }
        float acc = dv * inner + b;
        hpre[(size_t)v * 64 + lane] = acc;
        lsum += acc;
        lsq += acc * acc;
    }
    atomicAdd(&sred[lane], lsum);
    atomicAdd(&sred[64 + lane], lsq);
    __syncthreads();
    if (threadIdx.x < 128) atomicAdd(&stats[threadIdx.x], sred[threadIdx.x]);
}

// one block per graph: norm+relu layer-3 rows, register max/sum over the graph's
// contiguous node range, LDS tree-reduce, then fused head MLP. Zero atomics.
__global__ __launch_bounds__(256) void k_pool(const float* __restrict__ hpre,
                                              const float* __restrict__ stats,
                                              const float* __restrict__ gamma,
                                              const float* __restrict__ beta,
                                              const int* __restrict__ gstart,
                                              const float* __restrict__ lw1,
                                              const float* __restrict__ lb1,
                                              const float* __restrict__ lw2,
                                              const float* __restrict__ lb2,
                                              float* __restrict__ out) {
    __shared__ float smax[4][64];
    __shared__ float ssum[4][64];
    __shared__ float emb[192];
    __shared__ float hid[64];
    int g = blockIdx.x;
    int lane = threadIdx.x & 63;
    int wid = threadIdx.x >> 6;
    int s = gstart[g], e = gstart[g + 1];

    const float invN = 1.0f / (float)N_NODES;
    float mu = stats[lane] * invN;
    float var = stats[64 + lane] * invN - mu * mu;
    float sc = rsqrtf(var + EPSF) * gamma[lane];
    float sh = beta[lane] - mu * sc;

    float mx = 0.f, sm = 0.f;  // post-relu values are >= 0; empty graph -> 0 (matches ref)
    for (int v = s + wid; v < e; v += 4) {
        float h = fmaxf(hpre[(size_t)v * 64 + lane] * sc + sh, 0.f);
        mx = fmaxf(mx, h);
        sm += h;
    }
    smax[wid][lane] = mx;
    ssum[wid][lane] = sm;
    __syncthreads();
    if (wid == 0) {
        float m = fmaxf(fmaxf(smax[0][lane], smax[1][lane]), fmaxf(smax[2][lane], smax[3][lane]));
        float su = ssum[0][lane] + ssum[1][lane] + ssum[2][lane] + ssum[3][lane];
        float inv = 1.0f / fmaxf((float)(e - s), 1.0f);
        emb[lane] = m;
        emb[64 + lane] = su * inv;
        emb[128 + lane] = su;
    }
    __syncthreads();
    if (wid == 0) {
        float acc = lb1[lane];
        #pragma unroll 4
        for (int k = 0; k < 192; ++k) acc += emb[k] * lw1[k * 64 + lane];
        hid[lane] = fmaxf(acc, 0.f);
    }
    __syncthreads();
    if (threadIdx.x < N_CLASSES) {
        int j = threadIdx.x;
        float o = lb2[j];
        #pragma unroll 8
        for (int k = 0; k < 64; ++k) o += hid[k] * lw2[k * 10 + j];
        out[(size_t)g * 10 + j] = o;
    }
}

// ---------------- launch ----------------

extern "C" void kernel_launch(void* const* d_in, const int* in_sizes, int n_in,
                              void* d_out, int out_size, void* d_ws, size_t ws_size,
                              hipStream_t stream) {
    const float* x     = (const float*)d_in[0];
    const int* eidx    = (const int*)d_in[1];
    const int* batch   = (const int*)d_in[2];
    const float* W1    = (const float*)d_in[3];
    const float* b1    = (const float*)d_in[4];
    const float* W2    = (const float*)d_in[5];
    const float* b2    = (const float*)d_in[6];
    const float* gamma = (const float*)d_in[7];
    const float* beta  = (const float*)d_in[8];
    const float* lw1   = (const float*)d_in[9];
    const float* lb1   = (const float*)d_in[10];
    const float* lw2   = (const float*)d_in[11];
    const float* lb2   = (const float*)d_in[12];
    float* out = (float*)d_out;

    const int* e_src = eidx;
    const int* e_dst = eidx + N_EDGES;

    char* p = (char*)d_ws;
    auto carve = [&](size_t bytes) { char* r = p; p += (bytes + 255) & ~(size_t)255; return r; };
    // zero-initialized region (one memset covers these)
    int*   cnt   = (int*)carve((size_t)N_NODES * 4);
    float* stats = (float*)carve(3 * 128 * 4);
    size_t zero_bytes = (size_t)(p - (char*)d_ws);
    // scratch (no init needed)
    int*   offs   = (int*)carve((size_t)(N_NODES + 1) * 4);
    int*   cursor = (int*)carve((size_t)N_NODES * 4);
    float* dinv   = (float*)carve((size_t)N_NODES * 4);
    int*   gstart = (int*)carve((size_t)(N_GRAPHS + 1) * 4);
    int2*  csr    = (int2*)carve((size_t)N_EDGES * 8);
    unsigned short* B0 = (unsigned short*)carve((size_t)N_NODES * 64 * 2);  // bf16 h@W (gather src)
    float* B1     = (float*)carve((size_t)N_NODES * 64 * 4);                // fp32 h_pre

    hipMemsetAsync(d_ws, 0, zero_bytes, stream);

    // CSR by destination (reused for all 3 layers) + graph segment bounds
    k_hist<<<(N_EDGES + 255) / 256, 256, 0, stream>>>(e_dst, cnt);
    k_scan<<<1, 1024, 0, stream>>>(cnt, offs, cursor, dinv);
    k_fill<<<(N_EDGES + 255) / 256, 256, 0, stream>>>(e_src, e_dst, dinv, cursor, csr);
    k_bounds<<<(N_NODES + 255) / 256, 256, 0, stream>>>(batch, gstart);

    const int GEMM_GRID = (N_NODES + 63) / 64;  // 782
    // layer 1
    k_gemm<128, false><<<GEMM_GRID, 256, 0, stream>>>(x, W1, B0, nullptr, nullptr, nullptr);
    k_agg<<<2048, 256, 0, stream>>>(B0, offs, csr, dinv, b1, B1, stats);
    // layer 2 (norm+relu of layer 1 fused into A-stage)
    k_gemm<64, true><<<GEMM_GRID, 256, 0, stream>>>(B1, W2, B0, stats, gamma, beta);
    k_agg<<<2048, 256, 0, stream>>>(B0, offs, csr, dinv, b2, B1, stats + 128);
    // layer 3 (norm+relu of layer 2 fused into A-stage)
    k_gemm<64, true><<<GEMM_GRID, 256, 0, stream>>>(B1, W2, B0, stats + 128, gamma, beta);
    k_agg<<<2048, 256, 0, stream>>>(B0, offs, csr, dinv, b2, B1, stats + 256);
    // norm+relu layer 3 + segmented pooling + head MLP (no atomics)
    k_pool<<<N_GRAPHS, 256, 0, stream>>>(B1, stats + 256, gamma, beta, gstart,
                                         lw1, lb1, lw2, lb2, out);
}

// Round 9
// 570.273 us; speedup vs baseline: 1.3900x; 1.0330x over previous
//
#include <hip/hip_runtime.h>
#include <hip/hip_bf16.h>

#define N_NODES 50000
#define N_EDGES 1200000
#define F_IN 128
#define HID 64
#define N_CLASSES 10
#define N_GRAPHS 256
#define EPSF 1e-5f

__device__ __forceinline__ float bf2f(unsigned short u) {
    return __uint_as_float((unsigned)u << 16);
}
__device__ __forceinline__ unsigned short f2bf(float f) {
    __hip_bfloat16 h = __float2bfloat16(f);  // RNE
    return *reinterpret_cast<unsigned short*>(&h);
}

// ---------------- CSR build ----------------

__global__ void k_hist(const int* __restrict__ dst, int* __restrict__ cnt) {
    int e = blockIdx.x * blockDim.x + threadIdx.x;
    if (e < N_EDGES) atomicAdd(&cnt[dst[e]], 1);
}

// single-block exclusive scan over N_NODES ints; also emits dinv = rsqrt(cnt+1)
__global__ __launch_bounds__(1024) void k_scan(const int* __restrict__ cnt,
                                               int* __restrict__ offs,
                                               int* __restrict__ cursor,
                                               float* __restrict__ dinv) {
    __shared__ int wsum[16];
    __shared__ int s_carry;
    int tid = threadIdx.x;
    int lane = tid & 63, wid = tid >> 6;
    if (tid == 0) s_carry = 0;
    __syncthreads();
    for (int base = 0; base < N_NODES; base += 1024) {
        int i = base + tid;
        int v = (i < N_NODES) ? cnt[i] : 0;
        if (i < N_NODES) dinv[i] = rsqrtf((float)v + 1.0f);
        int x = v;
        #pragma unroll
        for (int d = 1; d < 64; d <<= 1) {
            int y = __shfl_up(x, (unsigned)d);
            if (lane >= d) x += y;
        }
        if (lane == 63) wsum[wid] = x;
        __syncthreads();
        if (tid == 0) {
            int run = 0;
            for (int w = 0; w < 16; ++w) { int t = wsum[w]; wsum[w] = run; run += t; }
        }
        __syncthreads();
        int carry = s_carry;
        int excl = carry + wsum[wid] + (x - v);
        if (i < N_NODES) { offs[i] = excl; cursor[i] = excl; }
        __syncthreads();
        if (tid == 1023) s_carry = carry + wsum[15] + x;  // waves 0-14 excl + wave15 incl
        __syncthreads();
    }
    if (tid == 0) offs[N_NODES] = s_carry;
}

// csr[pos] = (bf16(dinv[src])<<16) | src  — 4B entry (src < 65536), halves the
// scatter's distinct-line footprint (round-8: WRITE_SIZE was 64B per 8B write).
__global__ void k_fill(const int* __restrict__ esrc, const int* __restrict__ edst,
                       const float* __restrict__ dinv,
                       int* __restrict__ cursor, unsigned int* __restrict__ csr) {
    int e = blockIdx.x * blockDim.x + threadIdx.x;
    if (e < N_EDGES) {
        int d = edst[e];
        int s = esrc[e];
        int pos = atomicAdd(&cursor[d], 1);
        csr[pos] = ((unsigned)f2bf(dinv[s]) << 16) | (unsigned)s;
    }
}

// batch is sorted: gstart[g] = first node with batch >= g; gstart[N_GRAPHS] = N_NODES
__global__ void k_bounds(const int* __restrict__ batch, int* __restrict__ gstart) {
    int v = blockIdx.x * blockDim.x + threadIdx.x;
    if (v >= N_NODES) return;
    if (v == 0) {
        int b = batch[0];
        for (int g = 0; g <= b; ++g) gstart[g] = 0;
    } else {
        int b0 = batch[v - 1], b1 = batch[v];
        for (int g = b0 + 1; g <= b1; ++g) gstart[g] = v;
    }
    if (v == N_NODES - 1) {
        int b = batch[v];
        for (int g = b + 1; g <= N_GRAPHS; ++g) gstart[g] = N_NODES;
    }
}

// ---------------- dense layers ----------------

// out_bf[N,64] = bf16(A'[N,K] @ W[K,64]); 64x64 tile, 4x4 register micro-tile.
// NORM: A' = relu(A*sc[k] + sh[k]) — prev layer's BN+ReLU fused into the A-stage.
// bf16 output: consumer is k_agg's random gather (halves gather bytes).
// __launch_bounds__(256,2) caps VGPR<=128; bounded unroll (round-6 spill lesson).
template <int K, bool NORM>
__global__ __launch_bounds__(256, 2) void k_gemm(const float* __restrict__ A,
                                                 const float* __restrict__ W,
                                                 unsigned short* __restrict__ out_bf,
                                                 const float* __restrict__ stats,
                                                 const float* __restrict__ gamma,
                                                 const float* __restrict__ beta) {
    __shared__ float sW[K * 64];
    __shared__ float sA[32][68];   // transposed A-chunk, +4 pad (aligned b128 reads)
    __shared__ float ssc[128];
    __shared__ float ssh[128];
    int tid = threadIdx.x;
    for (int i = tid; i < K * 16; i += 256) ((float4*)sW)[i] = ((const float4*)W)[i];
    if (NORM && tid < K) {
        const float invN = 1.0f / (float)N_NODES;
        float mu = stats[tid] * invN;
        float var = stats[64 + tid] * invN - mu * mu;
        float sc = rsqrtf(var + EPSF) * gamma[tid];
        ssc[tid] = sc;
        ssh[tid] = beta[tid] - mu * sc;
    }
    __syncthreads();

    int row0 = blockIdx.x * 64;
    int c0 = (tid & 15) * 4;
    int r0 = (tid >> 4) * 4;
    float acc[4][4] = {};

    #pragma unroll 1
    for (int k0 = 0; k0 < K; k0 += 32) {
        #pragma unroll
        for (int i = 0; i < 2; ++i) {
            int idx = tid + i * 256;          // [0,512): row = idx/8, kq = idx%8
            int row = idx >> 3;
            int kq = idx & 7;
            int grow = row0 + row;
            float4 v = make_float4(0.f, 0.f, 0.f, 0.f);
            if (grow < N_NODES) v = *(const float4*)&A[(size_t)grow * K + k0 + kq * 4];
            if (NORM) {
                int kb = k0 + kq * 4;
                v.x = fmaxf(v.x * ssc[kb + 0] + ssh[kb + 0], 0.f);
                v.y = fmaxf(v.y * ssc[kb + 1] + ssh[kb + 1], 0.f);
                v.z = fmaxf(v.z * ssc[kb + 2] + ssh[kb + 2], 0.f);
                v.w = fmaxf(v.w * ssc[kb + 3] + ssh[kb + 3], 0.f);
            }
            sA[kq * 4 + 0][row] = v.x;
            sA[kq * 4 + 1][row] = v.y;
            sA[kq * 4 + 2][row] = v.z;
            sA[kq * 4 + 3][row] = v.w;
        }
        __syncthreads();
        #pragma unroll 4
        for (int k = 0; k < 32; ++k) {
            float4 a = *(const float4*)&sA[k][r0];
            float4 w = *(const float4*)&sW[(k0 + k) * 64 + c0];
            acc[0][0] += a.x * w.x; acc[0][1] += a.x * w.y; acc[0][2] += a.x * w.z; acc[0][3] += a.x * w.w;
            acc[1][0] += a.y * w.x; acc[1][1] += a.y * w.y; acc[1][2] += a.y * w.z; acc[1][3] += a.y * w.w;
            acc[2][0] += a.z * w.x; acc[2][1] += a.z * w.y; acc[2][2] += a.z * w.z; acc[2][3] += a.z * w.w;
            acc[3][0] += a.w * w.x; acc[3][1] += a.w * w.y; acc[3][2] += a.w * w.z; acc[3][3] += a.w * w.w;
        }
        __syncthreads();
    }
    #pragma unroll
    for (int i = 0; i < 4; ++i) {
        int row = row0 + r0 + i;
        if (row < N_NODES) {
            ushort4 o;
            o.x = f2bf(acc[i][0]); o.y = f2bf(acc[i][1]);
            o.z = f2bf(acc[i][2]); o.w = f2bf(acc[i][3]);
            *(ushort4*)&out_bf[(size_t)row * 64 + c0] = o;  // 8B aligned (c0%4==0)
        }
    }
}

// hpre[v] = dv * (dv*hw[v] + sum_u w_u*hw[u]) + b ; hw bf16, accum fp32.
// 16-wide gather batches: 32 loads in flight per drain window (round-8 lesson:
// k_agg is issue/drain-serialized, not fetch-bound — widen the batch).
__global__ __launch_bounds__(256) void k_agg(const unsigned short* __restrict__ hw,
                                             const int* __restrict__ offs,
                                             const unsigned int* __restrict__ csr,
                                             const float* __restrict__ dinv,
                                             const float* __restrict__ bias,
                                             float* __restrict__ hpre,
                                             float* __restrict__ stats) {
    __shared__ float sred[128];
    if (threadIdx.x < 128) sred[threadIdx.x] = 0.f;
    __syncthreads();
    int lane = threadIdx.x & 63;
    int wave = blockIdx.x * 4 + (threadIdx.x >> 6);
    int nw = gridDim.x * 4;
    float b = bias[lane];
    float lsum = 0.f, lsq = 0.f;
    for (int v = wave; v < N_NODES; v += nw) {
        float dv = dinv[v];
        int s = offs[v], e = offs[v + 1];
        float inner = dv * bf2f(hw[(size_t)v * 64 + lane]);
        int j = s;
        for (; j + 16 <= e; j += 16) {
            unsigned int q[16];
            #pragma unroll
            for (int t = 0; t < 16; ++t) q[t] = csr[j + t];
            float hh[16];
            #pragma unroll
            for (int t = 0; t < 16; ++t)
                hh[t] = bf2f(hw[(size_t)(q[t] & 0xFFFFu) * 64 + lane]);
            #pragma unroll
            for (int t = 0; t < 16; ++t)
                inner += bf2f((unsigned short)(q[t] >> 16)) * hh[t];
        }
        for (; j + 4 <= e; j += 4) {
            unsigned int q0 = csr[j], q1 = csr[j + 1], q2 = csr[j + 2], q3 = csr[j + 3];
            float h0 = bf2f(hw[(size_t)(q0 & 0xFFFFu) * 64 + lane]);
            float h1 = bf2f(hw[(size_t)(q1 & 0xFFFFu) * 64 + lane]);
            float h2 = bf2f(hw[(size_t)(q2 & 0xFFFFu) * 64 + lane]);
            float h3 = bf2f(hw[(size_t)(q3 & 0xFFFFu) * 64 + lane]);
            inner += bf2f((unsigned short)(q0 >> 16)) * h0;
            inner += bf2f((unsigned short)(q1 >> 16)) * h1;
            inner += bf2f((unsigned short)(q2 >> 16)) * h2;
            inner += bf2f((unsigned short)(q3 >> 16)) * h3;
        }
        for (; j < e; ++j) {
            unsigned int q = csr[j];
            inner += bf2f((unsigned short)(q >> 16)) * bf2f(hw[(size_t)(q & 0xFFFFu) * 64 + lane]);
        }
        float acc = dv * inner + b;
        hpre[(size_t)v * 64 + lane] = acc;
        lsum += acc;
        lsq += acc * acc;
    }
    atomicAdd(&sred[lane], lsum);
    atomicAdd(&sred[64 + lane], lsq);
    __syncthreads();
    if (threadIdx.x < 128) atomicAdd(&stats[threadIdx.x], sred[threadIdx.x]);
}

// one block per graph: norm+relu layer-3 rows, register max/sum over the graph's
// contiguous node range, LDS tree-reduce, then fused head MLP. Zero atomics.
__global__ __launch_bounds__(256) void k_pool(const float* __restrict__ hpre,
                                              const float* __restrict__ stats,
                                              const float* __restrict__ gamma,
                                              const float* __restrict__ beta,
                                              const int* __restrict__ gstart,
                                              const float* __restrict__ lw1,
                                              const float* __restrict__ lb1,
                                              const float* __restrict__ lw2,
                                              const float* __restrict__ lb2,
                                              float* __restrict__ out) {
    __shared__ float smax[4][64];
    __shared__ float ssum[4][64];
    __shared__ float emb[192];
    __shared__ float hid[64];
    int g = blockIdx.x;
    int lane = threadIdx.x & 63;
    int wid = threadIdx.x >> 6;
    int s = gstart[g], e = gstart[g + 1];

    const float invN = 1.0f / (float)N_NODES;
    float mu = stats[lane] * invN;
    float var = stats[64 + lane] * invN - mu * mu;
    float sc = rsqrtf(var + EPSF) * gamma[lane];
    float sh = beta[lane] - mu * sc;

    float mx = 0.f, sm = 0.f;  // post-relu values are >= 0; empty graph -> 0 (matches ref)
    for (int v = s + wid; v < e; v += 4) {
        float h = fmaxf(hpre[(size_t)v * 64 + lane] * sc + sh, 0.f);
        mx = fmaxf(mx, h);
        sm += h;
    }
    smax[wid][lane] = mx;
    ssum[wid][lane] = sm;
    __syncthreads();
    if (wid == 0) {
        float m = fmaxf(fmaxf(smax[0][lane], smax[1][lane]), fmaxf(smax[2][lane], smax[3][lane]));
        float su = ssum[0][lane] + ssum[1][lane] + ssum[2][lane] + ssum[3][lane];
        float inv = 1.0f / fmaxf((float)(e - s), 1.0f);
        emb[lane] = m;
        emb[64 + lane] = su * inv;
        emb[128 + lane] = su;
    }
    __syncthreads();
    if (wid == 0) {
        float acc = lb1[lane];
        #pragma unroll 4
        for (int k = 0; k < 192; ++k) acc += emb[k] * lw1[k * 64 + lane];
        hid[lane] = fmaxf(acc, 0.f);
    }
    __syncthreads();
    if (threadIdx.x < N_CLASSES) {
        int j = threadIdx.x;
        float o = lb2[j];
        #pragma unroll 8
        for (int k = 0; k < 64; ++k) o += hid[k] * lw2[k * 10 + j];
        out[(size_t)g * 10 + j] = o;
    }
}

// ---------------- launch ----------------

extern "C" void kernel_launch(void* const* d_in, const int* in_sizes, int n_in,
                              void* d_out, int out_size, void* d_ws, size_t ws_size,
                              hipStream_t stream) {
    const float* x     = (const float*)d_in[0];
    const int* eidx    = (const int*)d_in[1];
    const int* batch   = (const int*)d_in[2];
    const float* W1    = (const float*)d_in[3];
    const float* b1    = (const float*)d_in[4];
    const float* W2    = (const float*)d_in[5];
    const float* b2    = (const float*)d_in[6];
    const float* gamma = (const float*)d_in[7];
    const float* beta  = (const float*)d_in[8];
    const float* lw1   = (const float*)d_in[9];
    const float* lb1   = (const float*)d_in[10];
    const float* lw2   = (const float*)d_in[11];
    const float* lb2   = (const float*)d_in[12];
    float* out = (float*)d_out;

    const int* e_src = eidx;
    const int* e_dst = eidx + N_EDGES;

    char* p = (char*)d_ws;
    auto carve = [&](size_t bytes) { char* r = p; p += (bytes + 255) & ~(size_t)255; return r; };
    // zero-initialized region (one memset covers these)
    int*   cnt   = (int*)carve((size_t)N_NODES * 4);
    float* stats = (float*)carve(3 * 128 * 4);
    size_t zero_bytes = (size_t)(p - (char*)d_ws);
    // scratch (no init needed)
    int*   offs   = (int*)carve((size_t)(N_NODES + 1) * 4);
    int*   cursor = (int*)carve((size_t)N_NODES * 4);
    float* dinv   = (float*)carve((size_t)N_NODES * 4);
    int*   gstart = (int*)carve((size_t)(N_GRAPHS + 1) * 4);
    unsigned int* csr = (unsigned int*)carve((size_t)N_EDGES * 4);
    unsigned short* B0 = (unsigned short*)carve((size_t)N_NODES * 64 * 2);  // bf16 h@W (gather src)
    float* B1     = (float*)carve((size_t)N_NODES * 64 * 4);                // fp32 h_pre

    hipMemsetAsync(d_ws, 0, zero_bytes, stream);

    // CSR by destination (reused for all 3 layers) + graph segment bounds
    k_hist<<<(N_EDGES + 255) / 256, 256, 0, stream>>>(e_dst, cnt);
    k_scan<<<1, 1024, 0, stream>>>(cnt, offs, cursor, dinv);
    k_fill<<<(N_EDGES + 255) / 256, 256, 0, stream>>>(e_src, e_dst, dinv, cursor, csr);
    k_bounds<<<(N_NODES + 255) / 256, 256, 0, stream>>>(batch, gstart);

    const int GEMM_GRID = (N_NODES + 63) / 64;  // 782
    // layer 1
    k_gemm<128, false><<<GEMM_GRID, 256, 0, stream>>>(x, W1, B0, nullptr, nullptr, nullptr);
    k_agg<<<2048, 256, 0, stream>>>(B0, offs, csr, dinv, b1, B1, stats);
    // layer 2 (norm+relu of layer 1 fused into A-stage)
    k_gemm<64, true><<<GEMM_GRID, 256, 0, stream>>>(B1, W2, B0, stats, gamma, beta);
    k_agg<<<2048, 256, 0, stream>>>(B0, offs, csr, dinv, b2, B1, stats + 128);
    // layer 3 (norm+relu of layer 2 fused into A-stage)
    k_gemm<64, true><<<GEMM_GRID, 256, 0, stream>>>(B1, W2, B0, stats + 128, gamma, beta);
    k_agg<<<2048, 256, 0, stream>>>(B0, offs, csr, dinv, b2, B1, stats + 256);
    // norm+relu layer 3 + segmented pooling + head MLP (no atomics)
    k_pool<<<N_GRAPHS, 256, 0, stream>>>(B1, stats + 256, gamma, beta, gstart,
                                         lw1, lb1, lw2, lb2, out);
}